// Round 3
// baseline (105.847 us; speedup 1.0000x reference)
//
#include <hip/hip_runtime.h>
#include <hip/hip_bf16.h>

#define NN 8192
#define CC 256
// exp(x/0.01) = exp2(x * 100 * log2(e))
#define ESCALE 144.26950408889634f

typedef __attribute__((ext_vector_type(8))) short short8;
typedef __attribute__((ext_vector_type(4))) float f32x4;

typedef __attribute__((address_space(3))) unsigned int lds_u32;
typedef __attribute__((address_space(1))) const unsigned int glb_u32;

__device__ __forceinline__ void gload16(const ushort* g, ushort* l) {
  __builtin_amdgcn_global_load_lds((glb_u32*)(const void*)g, (lds_u32*)(void*)l, 16, 0, 0);
}

#define WAITV(n) asm volatile("s_waitcnt vmcnt(" #n ")" ::: "memory")

// ---------------- per-channel sum of squares (partials) ----------------
__global__ void colsumsq_kernel(const float* __restrict__ x, const float* __restrict__ y,
                                float* __restrict__ part) {
  const int b = blockIdx.x, t = threadIdx.x;
  const float* src = (b < 256) ? x : y;
  const int bb = b & 255;
  float s = 0.f;
#pragma unroll 4
  for (int r = 0; r < 32; ++r) {
    float v = src[(size_t)(bb * 32 + r) * CC + t];
    s = fmaf(v, v, s);
  }
  part[b * CC + t] = s;
}

// one wave per output norm: 512 outputs = 128 blocks x 4 waves
__global__ void finnorm_kernel(const float* __restrict__ part, float* __restrict__ inv_n) {
  const int g = blockIdx.x * 4 + (threadIdx.x >> 6);  // 0..511
  const int lane = threadIdx.x & 63;
  const int c = g & 255, T = g >> 8;
  float s = 0.f;
#pragma unroll
  for (int r = 0; r < 4; ++r)
    s += part[(size_t)((T << 8) + lane * 4 + r) * CC + c];
#pragma unroll
  for (int d = 1; d < 64; d <<= 1) s += __shfl_xor(s, d);
  if (lane == 0) inv_n[g] = 1.0f / sqrtf(s);
}

// ---------------- normalize + convert to bf16 (x and y fused) ----------------
__global__ void normconv_kernel(const float* __restrict__ x, const float* __restrict__ y,
                                const float* __restrict__ inv_n,
                                ushort* __restrict__ xnb, ushort* __restrict__ ynb) {
  int b = blockIdx.x;
  const float* src; ushort* dst; const float* inv;
  if (b < 2048) { src = x; dst = xnb; inv = inv_n; }
  else          { src = y; dst = ynb; inv = inv_n + 256; b -= 2048; }
  const int idx = (b * 256 + threadIdx.x) * 4;
  const float4 v = *(const float4*)(src + idx);
  const int c = idx & (CC - 1);
  __hip_bfloat16 h0 = __float2bfloat16(v.x * inv[c + 0]);
  __hip_bfloat16 h1 = __float2bfloat16(v.y * inv[c + 1]);
  __hip_bfloat16 h2 = __float2bfloat16(v.z * inv[c + 2]);
  __hip_bfloat16 h3 = __float2bfloat16(v.w * inv[c + 3]);
  ushort4 o;
  o.x = *(ushort*)&h0; o.y = *(ushort*)&h1; o.z = *(ushort*)&h2; o.w = *(ushort*)&h3;
  *(ushort4*)(dst + idx) = o;
}

// ---------------- main GEMM + fused epilogue ----------------
// 256x256 tile, 8 waves (2x4), BK=64, double-buffered LDS (128 KB), deep
// pipeline with counted vmcnt (never 0 in-loop), raw s_barrier, setprio.
// LDS: linear dest for global_load_lds + inverse-swizzled global SOURCE +
// swizzled ds_read (st_16x32: flip ushort-bit4 on row-bit2).
__global__ __launch_bounds__(512, 2)
void gemm_corr_kernel(const ushort* __restrict__ Xn, const ushort* __restrict__ Yn,
                      float* __restrict__ corr_top,     // [256][NN]
                      float* __restrict__ rowmax_part,  // [32][NN]  idx cb*NN + i
                      float* __restrict__ colsum_part)  // [32][NN]  idx rb*NN + j
{
  const int cb = blockIdx.x, rb = blockIdx.y;
  const int tid = threadIdx.x;
  const int lane = tid & 63, wid = tid >> 6;
  const int wr = wid >> 2, wc = wid & 3;   // 2 x 4 wave grid
  const int q = lane >> 4, lr = lane & 15;

  __shared__ __align__(16) ushort As[2][16384];   // [buf][256*64]
  __shared__ __align__(16) ushort Bs[2][16384];
  __shared__ float redmax[4][256];
  __shared__ float redsum[2][256];

  f32x4 acc[8][4];
#pragma unroll
  for (int m = 0; m < 8; ++m)
#pragma unroll
    for (int n = 0; n < 4; ++n) acc[m][n] = (f32x4){0.f, 0.f, 0.f, 0.f};

  // --- staging source map: chunk c = l*512 + tid ; linear LDS dest.
  // logical ushort = (c*8) ^ (((c>>5)&1)<<4) ; row = u>>6 ; ku = u&63
  const ushort* pA[4]; const ushort* pB[4];
#pragma unroll
  for (int l = 0; l < 4; ++l) {
    const int c = l * 512 + tid;
    const int u = (c * 8) ^ (((c >> 5) & 1) << 4);
    const int row = u >> 6, ku = u & 63;
    pA[l] = Xn + (size_t)(rb * 256 + row) * CC + ku;
    pB[l] = Yn + (size_t)(cb * 256 + row) * CC + ku;
  }

  auto stage = [&](int b, int kt) {
    const int koff = kt * 64;
#pragma unroll
    for (int l = 0; l < 4; ++l)
      gload16(pA[l] + koff, &As[b][(l * 512 + wid * 64) * 8]);
#pragma unroll
    for (int l = 0; l < 4; ++l)
      gload16(pB[l] + koff, &Bs[b][(l * 512 + wid * 64) * 8]);
  };

  // --- read-side swizzled indices ---
  const int aRowBase = (wr * 128 + lr) * 64 + q * 8;
  const int bRowBase = (wc * 64 + lr) * 64 + q * 8;
  const int sflip = (lr & 4) << 2;   // flip ushort-bit4 when row-bit2 set

  auto compute = [&](int b) {
#pragma unroll
    for (int ks = 0; ks < 2; ++ks) {
      short8 af[8], bf[4];
#pragma unroll
      for (int m = 0; m < 8; ++m)
        af[m] = *(const short8*)(&As[b][(aRowBase + m * 1024 + ks * 32) ^ sflip]);
#pragma unroll
      for (int n = 0; n < 4; ++n)
        bf[n] = *(const short8*)(&Bs[b][(bRowBase + n * 1024 + ks * 32) ^ sflip]);
      __builtin_amdgcn_s_setprio(1);
#pragma unroll
      for (int m = 0; m < 8; ++m)
#pragma unroll
        for (int n = 0; n < 4; ++n)
          acc[m][n] = __builtin_amdgcn_mfma_f32_16x16x32_bf16(af[m], bf[n], acc[m][n], 0, 0, 0);
      __builtin_amdgcn_s_setprio(0);
    }
  };

  // --- pipeline: 4 K-tiles, 2-deep, counted vmcnt ---
  stage(0, 0);
  stage(1, 1);                                   // 16 outstanding / wave

  WAITV(8); __builtin_amdgcn_s_barrier();        // kt0 resident everywhere
  __builtin_amdgcn_sched_barrier(0);
  compute(0);
  __builtin_amdgcn_sched_barrier(0);
  __builtin_amdgcn_s_barrier();                  // all reads of buf0 done
  __builtin_amdgcn_sched_barrier(0);
  stage(0, 2);                                   // 16 outstanding

  WAITV(8); __builtin_amdgcn_s_barrier();
  __builtin_amdgcn_sched_barrier(0);
  compute(1);
  __builtin_amdgcn_sched_barrier(0);
  __builtin_amdgcn_s_barrier();
  __builtin_amdgcn_sched_barrier(0);
  stage(1, 3);                                   // 16 outstanding

  WAITV(8); __builtin_amdgcn_s_barrier();
  __builtin_amdgcn_sched_barrier(0);
  compute(0);

  WAITV(0); __builtin_amdgcn_s_barrier();
  __builtin_amdgcn_sched_barrier(0);
  compute(1);

  // ---- epilogue ----
  // C/D map: row = rb*256 + wr*128 + m*16 + q*4 + r ; col = cb*256 + wc*64 + n*16 + lr
  if (rb == 0) {
    const int colg = cb * 256 + wc * 64 + lr;
#pragma unroll
    for (int m = 0; m < 8; ++m) {
      const int rowg = wr * 128 + m * 16 + q * 4;
#pragma unroll
      for (int n = 0; n < 4; ++n)
#pragma unroll
        for (int r = 0; r < 4; ++r)
          corr_top[(size_t)(rowg + r) * NN + colg + n * 16] = acc[m][n][r];
    }
  }

  // row max over this block's 256 columns
#pragma unroll
  for (int m = 0; m < 8; ++m)
#pragma unroll
    for (int r = 0; r < 4; ++r) {
      float t = fmaxf(fmaxf(acc[m][0][r], acc[m][1][r]), fmaxf(acc[m][2][r], acc[m][3][r]));
      t = fmaxf(t, __shfl_xor(t, 1));
      t = fmaxf(t, __shfl_xor(t, 2));
      t = fmaxf(t, __shfl_xor(t, 4));
      t = fmaxf(t, __shfl_xor(t, 8));
      if (lr == 0) redmax[wc][wr * 128 + m * 16 + q * 4 + r] = t;
    }
  __syncthreads();
  if (tid < 256) {
    float v = fmaxf(fmaxf(redmax[0][tid], redmax[1][tid]),
                    fmaxf(redmax[2][tid], redmax[3][tid]));
    rowmax_part[(size_t)cb * NN + rb * 256 + tid] = v;
  }

  // column sum of exp over this block's 256 rows
#pragma unroll
  for (int n = 0; n < 4; ++n) {
    float s = 0.f;
#pragma unroll
    for (int m = 0; m < 8; ++m)
#pragma unroll
      for (int r = 0; r < 4; ++r)
        s += exp2f(acc[m][n][r] * ESCALE);
    s += __shfl_xor(s, 16);
    s += __shfl_xor(s, 32);
    if (lane < 16) redsum[wr][wc * 64 + n * 16 + lr] = s;
  }
  __syncthreads();
  if (tid < 256)
    colsum_part[(size_t)rb * NN + cb * 256 + tid] = redsum[0][tid] + redsum[1][tid];
}

// ---------------- fused reductions: thread per output, coalesced ----------------
__global__ void reduce_both_kernel(const float* __restrict__ rowmax_part,
                                   const float* __restrict__ colsum_part,
                                   float* __restrict__ out, float* __restrict__ inv_s) {
  const int g = blockIdx.x * 256 + threadIdx.x;   // [0, 16384)
  if (g < 8192) {
    float m = -3.4e38f;
#pragma unroll
    for (int b = 0; b < 32; ++b) m = fmaxf(m, rowmax_part[(size_t)b * NN + g]);
    out[256 + g] = m;
  } else {
    const int j = g - 8192;
    float s = 0.f;
#pragma unroll
    for (int b = 0; b < 32; ++b) s += colsum_part[(size_t)b * NN + j];
    inv_s[j] = 1.0f / s;
  }
}

// ---------------- warped color: one block per k<256 (reads normalized ynb) ----
__global__ void warped_kernel(const float* __restrict__ corr_top, const float* __restrict__ inv_s,
                              const ushort* __restrict__ ynb, float* __restrict__ out) {
  const int k = blockIdx.x;
  const int tid = threadIdx.x;
  float p = 0.f;
  for (int j = tid; j < NN; j += 256) {
    float e = exp2f(corr_top[(size_t)k * NN + j] * ESCALE);
    float yv = __uint_as_float((unsigned)ynb[(size_t)j * CC + k] << 16);
    p += e * inv_s[j] * yv;
  }
#pragma unroll
  for (int d = 1; d < 64; d <<= 1) p += __shfl_xor(p, d);
  __shared__ float wsum[4];
  if ((tid & 63) == 0) wsum[tid >> 6] = p;
  __syncthreads();
  if (tid == 0) out[k] = wsum[0] + wsum[1] + wsum[2] + wsum[3];
}

extern "C" void kernel_launch(void* const* d_in, const int* in_sizes, int n_in,
                              void* d_out, int out_size, void* d_ws, size_t ws_size,
                              hipStream_t stream) {
  const float* x = (const float*)d_in[0];
  const float* y = (const float*)d_in[1];
  float* out = (float*)d_out;
  char* ws = (char*)d_ws;

  ushort* xnb        = (ushort*)(ws);                        // 4 MB
  ushort* ynb        = (ushort*)(ws + (4u << 20));           // 4 MB
  float*  corr_top   = (float*)(ws + (8u << 20));            // 8 MB
  float*  rowmax_prt = (float*)(ws + (16u << 20));           // 1 MB
  float*  colsum_prt = (float*)(ws + (17u << 20));           // 1 MB
  float*  part       = (float*)(ws + (18u << 20));           // 512 KB
  float*  inv_n      = (float*)(ws + (18u << 20) + 524288);  // 2 KB
  float*  inv_s      = (float*)(ws + (18u << 20) + 524288 + 4096); // 32 KB

  colsumsq_kernel<<<512, 256, 0, stream>>>(x, y, part);
  finnorm_kernel<<<128, 256, 0, stream>>>(part, inv_n);
  normconv_kernel<<<4096, 256, 0, stream>>>(x, y, inv_n, xnb, ynb);
  gemm_corr_kernel<<<dim3(32, 32), 512, 0, stream>>>(xnb, ynb, corr_top, rowmax_prt, colsum_prt);
  reduce_both_kernel<<<64, 256, 0, stream>>>(rowmax_prt, colsum_prt, out, inv_s);
  warped_kernel<<<256, 256, 0, stream>>>(corr_top, inv_s, ynb, out);
}